// Round 4
// baseline (279.977 us; speedup 1.0000x reference)
//
#include <hip/hip_runtime.h>
#include <hip/hip_bf16.h>

#define B_ 2
#define S_ 8192
#define DIM_ 1024
#define NH_ 16
#define NKV_ 4
#define HD_ 64
#define NC_ 64

typedef __bf16 bf16x8 __attribute__((ext_vector_type(8)));
typedef float f32x4 __attribute__((ext_vector_type(4)));
using bf16 = __hip_bfloat16;

// async global->LDS, 16B per lane; LDS dst = base + lane*16 (wave-uniform base)
#define ASYNC16(gp, lp) __builtin_amdgcn_global_load_lds( \
    (__attribute__((address_space(1))) void*)(void*)(gp), \
    (__attribute__((address_space(3))) void*)(void*)(lp), 16, 0, 0)

// ---------------- fused prep: x->bf16, weights->bf16, rope tables ----------------
__global__ __launch_bounds__(256) void prep_kernel(const float* __restrict__ x, const float* __restrict__ Wq,
                                                   const float* __restrict__ Wk, const float* __restrict__ Wv,
                                                   const float* __restrict__ Wo, bf16* __restrict__ xb,
                                                   bf16* __restrict__ wqkv, bf16* __restrict__ wo,
                                                   float* __restrict__ cosd, float* __restrict__ sind) {
    int bid = blockIdx.x;
    if (bid < 16384) {  // x convert: 16,777,216 elems
        size_t i = ((size_t)bid * 256 + threadIdx.x) * 4;
        const float4 f = *(const float4*)(x + i);
        bf16 t[4];
        t[0] = __float2bfloat16(f.x); t[1] = __float2bfloat16(f.y);
        t[2] = __float2bfloat16(f.z); t[3] = __float2bfloat16(f.w);
        *(uint2*)(xb + i) = *(const uint2*)t;
    } else if (bid < 18944) {  // weights: Wq|Wk|Wv -> wqkv, Wo -> wo
        size_t e = ((size_t)(bid - 16384) * 256 + threadIdx.x) * 4;
        const float* src;
        bf16* dst;
        if (e < 1048576)        { src = Wq + e;             dst = wqkv + e; }
        else if (e < 1310720)   { src = Wk + (e - 1048576); dst = wqkv + e; }
        else if (e < 1572864)   { src = Wv + (e - 1310720); dst = wqkv + e; }
        else                    { src = Wo + (e - 1572864); dst = wo + (e - 1572864); }
        const float4 f = *(const float4*)src;
        bf16 t[4];
        t[0] = __float2bfloat16(f.x); t[1] = __float2bfloat16(f.y);
        t[2] = __float2bfloat16(f.z); t[3] = __float2bfloat16(f.w);
        *(uint2*)dst = *(const uint2*)t;
    } else {  // rope tables: S_*32 entries, f64 range-reduction + hw sin/cos
        int idx = (bid - 18944) * 256 + threadIdx.x;
        int s = idx >> 5, i = idx & 31;
        double inv = exp((double)i * (-9.210340371976184 / 32.0));  // 10000^(-i/32)
        double rev = ((double)s * inv) * 0.15915494309189535;       // angle / 2pi
        double frac = rev - floor(rev);
        float a = (float)frac * 6.2831853071795865f;
        cosd[idx] = __cosf(a);
        sind[idx] = __sinf(a);
    }
}

// ---------------- C[M][N] = A[M][K]*B[N][K]^T, bf16 in, OT out ----------------
// R2 decision: 128^2 m97-structure is the keeper. 8-phase 256^2 measured 715 TF here
// (2-phase level; K=1024 too short to amortize -- m248's full-stack = 848 TF at this K),
// vs this kernel's proven 876 TF at 3 blocks/CU. Do not revisit without new evidence.
// grid (M/128, N/128): x = M-tile so blocks sharing an A-tile have equal id%8 (same XCD).
// Columns < rope_ncols get RoPE applied in the epilogue (wave-uniform: 64-col strips).
template <typename OT>
__global__ __launch_bounds__(256, 3) void gemm_bt_kernel(const bf16* __restrict__ A, const bf16* __restrict__ Bm,
                                                         OT* __restrict__ C, int M, int N, int K, int rope_ncols,
                                                         const float* __restrict__ cosd,
                                                         const float* __restrict__ sind) {
    __shared__ bf16 As[128 * 64];
    __shared__ bf16 Bs[128 * 64];
    const int tid = threadIdx.x;
    const int bm = blockIdx.x * 128, bn = blockIdx.y * 128;
    const int wave = tid >> 6, lane = tid & 63;
    const int wm = (wave >> 1) * 64, wn = (wave & 1) * 64;
    const int lr = lane & 15, quad = lane >> 4;
    const int srow = wave * 32;
    const int lrow = lane >> 3;                        // 0..7
    const int lchunk = ((lane & 7) ^ lrow) * 8;        // XOR-swizzled source chunk (elems)
    const bf16* Ag = A + (size_t)(bm + srow + lrow) * K + lchunk;
    const bf16* Bg = Bm + (size_t)(bn + srow + lrow) * K + lchunk;
    f32x4 acc[4][4] = {};
    for (int k0 = 0; k0 < K; k0 += 64) {
#pragma unroll
        for (int p = 0; p < 4; ++p) {
            ASYNC16(Ag + (size_t)(p * 8) * K + k0, &As[(srow + p * 8) * 64]);
            ASYNC16(Bg + (size_t)(p * 8) * K + k0, &Bs[(srow + p * 8) * 64]);
        }
        __syncthreads();
#pragma unroll
        for (int kk = 0; kk < 64; kk += 32) {
            const int sw = (((kk >> 3) + quad) ^ (lr & 7)) << 3;  // de-swizzled chunk offset
            bf16x8 af[4], bfr[4];
#pragma unroll
            for (int i = 0; i < 4; ++i) af[i] = *(const bf16x8*)(&As[(wm + i * 16 + lr) * 64 + sw]);
#pragma unroll
            for (int i = 0; i < 4; ++i) bfr[i] = *(const bf16x8*)(&Bs[(wn + i * 16 + lr) * 64 + sw]);
#pragma unroll
            for (int mi = 0; mi < 4; ++mi)
#pragma unroll
                for (int ni = 0; ni < 4; ++ni)
                    acc[mi][ni] = __builtin_amdgcn_mfma_f32_16x16x32_bf16(af[mi], bfr[ni], acc[mi][ni], 0, 0, 0);
        }
        __syncthreads();
    }
    if (bn + wn < rope_ncols) {
        // wave's 64 columns = exactly one head; pair (i, i+32) = (acc[mi][ni], acc[mi][ni+2])
#pragma unroll
        for (int mi = 0; mi < 4; ++mi)
#pragma unroll
            for (int r = 0; r < 4; ++r) {
                int row = bm + wm + mi * 16 + quad * 4 + r;
                int s = row & (S_ - 1);
#pragma unroll
                for (int ni = 0; ni < 2; ++ni) {
                    int i = ni * 16 + lr;
                    float cs = cosd[(s << 5) + i];
                    float sn = sind[(s << 5) + i];
                    float x1 = acc[mi][ni][r], x2 = acc[mi][ni + 2][r];
                    acc[mi][ni][r] = x1 * cs - x2 * sn;
                    acc[mi][ni + 2][r] = x2 * cs + x1 * sn;
                }
            }
    }
#pragma unroll
    for (int mi = 0; mi < 4; ++mi)
#pragma unroll
        for (int ni = 0; ni < 4; ++ni)
#pragma unroll
            for (int r = 0; r < 4; ++r) {
                int row = bm + wm + mi * 16 + quad * 4 + r;
                int col = bn + wn + ni * 16 + lr;
                float v = acc[mi][ni][r];
                if constexpr (__is_same(OT, float)) C[(size_t)row * N + col] = v;
                else C[(size_t)row * N + col] = __float2bfloat16(v);
            }
}

// XOR chunk swizzle for transposed LDS tiles (row stride 136 elems, b128-aligned):
// element (row e, col t): addr = e*136 + ((chunk & ~7)<<3) + (((chunk ^ (e>>3)) & 7)<<3) + (t&7),
// chunk = t>>3. Bit 3 of chunk MUST be kept (cols 0..127 -> chunk 0..15); dropping it
// aliases t and t+64 (the R4 NaN bug). Transpose stores hit 8 distinct banks; b128 reads aligned.

// ---------------- per-chunk KV contribution, PER-GROUP: all 4 heads of group g ----------------
// C_h[e][d] = sum_t v[t][e]*kdec_h[t]*k[t][d]. kdec multiplies along the MFMA K-dim (t), so it
// attaches to EITHER operand; moving it to the v-side A-frag lets k/v be staged RAW and ONCE
// per group (was 4x redundant per-head staging). 512 thr = 8 waves: wave w -> e-block
// (w&3)*16, head-pair (w>>2)*2. A-frag t-mapping: frag at chunk qa holds t = qa*8 + i
// (i=0..7), qa = (ks>>3)+quad -> kdec(t) = exp(-slope*(127-ks-quad*8)) * exp(slope)^i,
// applied as serial multiply chain in f32, rounded to bf16 (same rounding class as the old
// k-side bf16 product). LDS 34.8 KB -> 4 blocks/CU (32 waves).
__global__ __launch_bounds__(512) void chunk_kv_kernel(const bf16* __restrict__ qkv, bf16* __restrict__ Cout) {
    const int j = blockIdx.x, g = blockIdx.y, b = blockIdx.z;
    __shared__ bf16 kT[64 * 136];
    __shared__ bf16 vT[64 * 136];
    const int tid = threadIdx.x;
#pragma unroll
    for (int p = 0; p < 2; ++p) {
        int flat = p * 512 + tid;
        int t = flat >> 3, d0 = (flat & 7) * 8;
        const size_t row = (size_t)(b * S_ + j * 128 + t);
        uint4 kw = *(const uint4*)(qkv + row * 1536 + 1024 + g * 64 + d0);
        uint4 vw = *(const uint4*)(qkv + row * 1536 + 1280 + g * 64 + d0);
        const bf16* kp = (const bf16*)&kw;
        const bf16* vp = (const bf16*)&vw;
#pragma unroll
        for (int i = 0; i < 8; ++i) {
            int e = d0 + i;
            int sw = (((t >> 3) & ~7) << 3) + ((((t >> 3) ^ (e >> 3)) & 7) << 3) + (t & 7);
            kT[e * 136 + sw] = kp[i];
            vT[e * 136 + sw] = vp[i];
        }
    }
    __syncthreads();
    const int wave = tid >> 6, lane = tid & 63, lr = lane & 15, quad = lane >> 4;
    const int eblk = (wave & 3) * 16;
    const int hp = (wave >> 2) * 2;   // heads g*4+hp, g*4+hp+1
    f32x4 acc[2][4] = {};
    float slope[2], g1[2];
#pragma unroll
    for (int hh = 0; hh < 2; ++hh) {
        slope[hh] = exp2f(-0.5f * (float)(g * 4 + hp + hh + 1));
        g1[hh] = __expf(slope[hh]);
    }
#pragma unroll
    for (int ks = 0; ks < 128; ks += 32) {
        int qa = (ks >> 3) + quad;
        int qhi = (qa & ~7) << 3;
        int ea = eblk + lr;
        bf16x8 a = *(const bf16x8*)(&vT[ea * 136 + qhi + (((qa ^ (ea >> 3)) & 7) << 3)]);
        float av[8];
#pragma unroll
        for (int i = 0; i < 8; ++i) av[i] = (float)a[i];
        bf16x8 bb[4];
#pragma unroll
        for (int ni = 0; ni < 4; ++ni) {
            int eb = ni * 16 + lr;
            bb[ni] = *(const bf16x8*)(&kT[eb * 136 + qhi + (((qa ^ (eb >> 3)) & 7) << 3)]);
        }
#pragma unroll
        for (int hh = 0; hh < 2; ++hh) {
            float m = __expf(-slope[hh] * (float)(127 - ks - quad * 8));
            bf16x8 as;
#pragma unroll
            for (int i = 0; i < 8; ++i) { as[i] = (__bf16)(av[i] * m); m *= g1[hh]; }
#pragma unroll
            for (int ni = 0; ni < 4; ++ni)
                acc[hh][ni] = __builtin_amdgcn_mfma_f32_16x16x32_bf16(as, bb[ni], acc[hh][ni], 0, 0, 0);
        }
    }
#pragma unroll
    for (int hh = 0; hh < 2; ++hh) {
        int h = g * 4 + hp + hh;
        bf16* out = Cout + ((size_t)((b * NH_ + h) * NC_ + j)) * 4096;
#pragma unroll
        for (int ni = 0; ni < 4; ++ni)
#pragma unroll
            for (int r = 0; r < 4; ++r)
                out[(eblk + quad * 4 + r) * 64 + ni * 16 + lr] = __float2bfloat16(acc[hh][ni][r]);
    }
}

// ---------------- exclusive decay scan: one (bh,e,d) lane per thread, coalesced ----------------
__global__ __launch_bounds__(256) void scan_kv_kernel(const bf16* __restrict__ Cin, bf16* __restrict__ st) {
    const int bh = blockIdx.x >> 4;                       // 16 blocks per bh
    const int f = ((blockIdx.x & 15) << 8) + threadIdx.x; // 0..4095
    const int h = bh & (NH_ - 1);
    const float slope = exp2f(-0.5f * (float)(h + 1));
    const float bdec = __expf(-slope * 128.0f);
    const bf16* Cb = Cin + (size_t)bh * NC_ * 4096 + f;
    bf16* sb = st + (size_t)bh * NC_ * 4096 + f;
    float carry = 0.f;
#pragma unroll 8
    for (int c = 0; c < NC_; ++c) {
        sb[(size_t)c * 4096] = __float2bfloat16(carry);
        carry = bdec * carry + __bfloat162float(Cb[(size_t)c * 4096]);
    }
}

// ---------------- per-chunk output: O = (mask ∘ qk^T) v + (q*qdec) kv ----------------
// R4 restructure: 512 thr = 8 waves, 16 rows/wave (was 4x32). Per-wave state halves
// (sacc[8]+oacc[4] = 48 VGPR), per-thread serial chains halve (32 P-writes, 2 vT stages),
// occupancy 12 -> 16 waves/CU (2 blocks/CU @ <=128 VGPR; LDS 52.2 KB allows 3).
// T14: v-tile global loads issued at kernel top (2x uint4/thread), LDS-written in phase 3.
// q-frags cached in regs across QK^T and qKV (saves qs re-read).
// LDS overlay: phase1 {qs[128][64], kbs[128][64]} (chunk-XOR swizzled, ASYNC16-staged);
// phase2 {Ps[128][136], vT[64][136]} swizzled. Union 26112 elems = 52.2 KB.
__global__ __launch_bounds__(512, 2) void attn_chunk_kernel(const bf16* __restrict__ qkv,
                                                            const bf16* __restrict__ kvst,
                                                            bf16* __restrict__ outb) {
    const int c = blockIdx.x, h = blockIdx.y, b = blockIdx.z;
    const int g = h >> 2;
    const float slope = exp2f(-0.5f * (float)(h + 1));
    __shared__ bf16 smem[26112];
    bf16* qs  = smem;            // phase1: [128][64] chunk-XOR swizzled
    bf16* kbs = smem + 8192;     // phase1: [128][64] chunk-XOR swizzled
    bf16* Ps  = smem;            // phase2: [128][136] swizzled
    bf16* vT  = smem + 17408;    // phase2: [64][136] swizzled
    const int tid = threadIdx.x;
    const int wave = tid >> 6, lane = tid & 63, lr = lane & 15, quad = lane >> 4;
    const int srow = lane >> 3;                  // 0..7
    const int schunk = ((lane & 7) ^ srow) * 8;  // pre-swizzled source chunk (elems)
    // T14 early-issue: v-tile loads at top; land during QK^T/qKV; written to LDS in phase 3
    uint4 vreg[2];
#pragma unroll
    for (int p = 0; p < 2; ++p) {
        int flat = p * 512 + tid;
        int t = flat >> 3, d0 = (flat & 7) * 8;
        size_t row = (size_t)(b * S_ + c * 128 + t);
        vreg[p] = *(const uint4*)(qkv + row * 1536 + 1280 + g * 64 + d0);
    }
    // stage q/k via ASYNC16 (8 waves x 2 row-groups each covers 16 groups of 8 rows)
#pragma unroll
    for (int p = 0; p < 2; ++p) {
        int t0 = (wave + p * 8) * 8;
        size_t row = (size_t)(b * S_ + c * 128 + t0 + srow);
        ASYNC16(qkv + row * 1536 + h * 64 + schunk, &qs[t0 * 64]);
        ASYNC16(qkv + row * 1536 + 1024 + g * 64 + schunk, &kbs[t0 * 64]);
    }
    asm volatile("s_waitcnt vmcnt(0)");
    __syncthreads();
    const int m0 = wave * 16;
    // q-frags cached: reused by QK^T and qKV (row m0+lr, t&7 == lr&7)
    bf16x8 qf[2];
#pragma unroll
    for (int kk = 0; kk < 2; ++kk)
        qf[kk] = *(const bf16x8*)(&qs[(m0 + lr) * 64 + ((((kk * 4 + quad)) ^ (lr & 7)) & 7) * 8]);
    f32x4 sacc[8] = {};
#pragma unroll
    for (int kk = 0; kk < 2; ++kk) {
        const int sw = (((kk * 4 + quad) ^ (lr & 7)) & 7) << 3;
#pragma unroll
        for (int ni = 0; ni < 8; ++ni) {
            bf16x8 bfr = *(const bf16x8*)(&kbs[(ni * 16 + lr) * 64 + sw]);
            sacc[ni] = __builtin_amdgcn_mfma_f32_16x16x32_bf16(qf[kk], bfr, sacc[ni], 0, 0, 0);
        }
    }
    // qKV term from scanned state (global, L2/L3-resident)
    f32x4 oacc[4] = {};
    const bf16* kvb = kvst + ((size_t)((b * NH_ + h) * NC_ + c)) * 4096;
    float qd = __expf(-slope * (float)(m0 + lr + 1));
#pragma unroll
    for (int kk = 0; kk < 2; ++kk) {
        bf16x8 a0;
#pragma unroll
        for (int i = 0; i < 8; ++i) a0[i] = (__bf16)((float)qf[kk][i] * qd);
#pragma unroll
        for (int ni = 0; ni < 4; ++ni) {
            bf16x8 bk = *(const bf16x8*)(kvb + (ni * 16 + lr) * 64 + kk * 32 + quad * 8);
            oacc[ni] = __builtin_amdgcn_mfma_f32_16x16x32_bf16(a0, bk, oacc[ni], 0, 0, 0);
        }
    }
    __syncthreads();  // qs/kbs fully consumed; region reused for Ps/vT
    // factorized mask: exp(-s*(t-tp)) = exp(-s*(t-m0)) * exp(-s*max(m0-tp,-15))
    // (t-m0 = quad*4+r <= 15, so clamp -15 is exact for all unmasked entries)
    float ftv[4], gtv[8];
#pragma unroll
    for (int r = 0; r < 4; ++r) ftv[r] = __expf(-slope * (float)(quad * 4 + r));
#pragma unroll
    for (int ni = 0; ni < 8; ++ni)
        gtv[ni] = __expf(-slope * fmaxf((float)(m0 - (ni * 16 + lr)), -15.0f));
#pragma unroll
    for (int ni = 0; ni < 8; ++ni)
#pragma unroll
        for (int r = 0; r < 4; ++r) {
            int t = m0 + quad * 4 + r;
            int tp = ni * 16 + lr;
            float val = (t >= tp) ? sacc[ni][r] * ftv[r] * gtv[ni] : 0.f;
            int sw = (((tp >> 3) & ~7) << 3) + ((((tp >> 3) ^ (t >> 3)) & 7) << 3) + (tp & 7);
            Ps[t * 136 + sw] = __float2bfloat16(val);
        }
    // write v transposed (swizzled) from the early-issued regs
#pragma unroll
    for (int p = 0; p < 2; ++p) {
        int flat = p * 512 + tid;
        int t = flat >> 3, d0 = (flat & 7) * 8;
        const bf16* vp = (const bf16*)&vreg[p];
#pragma unroll
        for (int i = 0; i < 8; ++i) {
            int e = d0 + i;
            int sw = (((t >> 3) & ~7) << 3) + ((((t >> 3) ^ (e >> 3)) & 7) << 3) + (t & 7);
            vT[e * 136 + sw] = vp[i];
        }
    }
    __syncthreads();
#pragma unroll
    for (int ks2 = 0; ks2 < 128; ks2 += 32) {
        int qa = (ks2 >> 3) + quad;             // chunk index 0..15
        int qhi = (qa & ~7) << 3;
        int ra0 = m0 + lr;
        bf16x8 af0 = *(const bf16x8*)(&Ps[ra0 * 136 + qhi + (((qa ^ (ra0 >> 3)) & 7) << 3)]);
#pragma unroll
        for (int ni = 0; ni < 4; ++ni) {
            int eb = ni * 16 + lr;
            bf16x8 bfv = *(const bf16x8*)(&vT[eb * 136 + qhi + (((qa ^ (eb >> 3)) & 7) << 3)]);
            oacc[ni] = __builtin_amdgcn_mfma_f32_16x16x32_bf16(af0, bfv, oacc[ni], 0, 0, 0);
        }
    }
#pragma unroll
    for (int ni = 0; ni < 4; ++ni)
#pragma unroll
        for (int r = 0; r < 4; ++r) {
            int t = m0 + quad * 4 + r;
            int e = ni * 16 + lr;
            size_t row = (size_t)(b * S_ + c * 128 + t);
            outb[row * (NH_ * 64) + h * 64 + e] = __float2bfloat16(oacc[ni][r]);
        }
}

extern "C" void kernel_launch(void* const* d_in, const int* in_sizes, int n_in,
                              void* d_out, int out_size, void* d_ws, size_t ws_size,
                              hipStream_t stream) {
    (void)in_sizes; (void)n_in; (void)out_size; (void)ws_size;
    const float* x  = (const float*)d_in[0];
    const float* Wq = (const float*)d_in[1];
    const float* Wk = (const float*)d_in[2];
    const float* Wv = (const float*)d_in[3];
    const float* Wo = (const float*)d_in[4];
    float* out = (float*)d_out;
    char* ws = (char*)d_ws;
    bf16*  xb    = (bf16*)(ws);                    // 33,554,432 (reused as attn_out)
    bf16*  qkvb  = (bf16*)(ws + 33554432);         // 50,331,648  [M][1536]: q|k|v
    bf16*  wqkvb = (bf16*)(ws + 83886080);         //  3,145,728  [1536][1024]
    bf16*  wob   = (bf16*)(ws + 87031808);         //  2,097,152
    float* cosd  = (float*)(ws + 89128960);        //  1,048,576
    float* sind  = (float*)(ws + 90177536);        //  1,048,576
    bf16*  Cbuf  = (bf16*)(ws + 91226112);         // 16,777,216
    bf16*  kvst  = (bf16*)(ws + 108003328);        // 16,777,216  -> total 124,780,544 B
    bf16*  attn  = xb;

    prep_kernel<<<19968, 256, 0, stream>>>(x, Wq, Wk, Wv, Wo, xb, wqkvb, wob, cosd, sind);

    // fused q|k|v projection with RoPE on cols < 1280 (q heads + k heads)
    gemm_bt_kernel<bf16><<<dim3(128, 12), 256, 0, stream>>>(xb, wqkvb, qkvb, 16384, 1536, 1024, 1280, cosd, sind);

    // per-GROUP chunk KV (4 heads/block, raw k/v staged once)
    chunk_kv_kernel<<<dim3(NC_, NKV_, B_), 512, 0, stream>>>(qkvb, Cbuf);
    scan_kv_kernel<<<512, 256, 0, stream>>>(Cbuf, kvst);
    attn_chunk_kernel<<<dim3(NC_, NH_, B_), 512, 0, stream>>>(qkvb, kvst, attn);

    gemm_bt_kernel<float><<<dim3(128, 8), 256, 0, stream>>>(attn, wob, out, 16384, 1024, 1024, 0, cosd, sind);
}

// Round 5
// 271.699 us; speedup vs baseline: 1.0305x; 1.0305x over previous
//
#include <hip/hip_runtime.h>
#include <hip/hip_bf16.h>

#define B_ 2
#define S_ 8192
#define DIM_ 1024
#define NH_ 16
#define NKV_ 4
#define HD_ 64
#define NC_ 64

typedef __bf16 bf16x8 __attribute__((ext_vector_type(8)));
typedef float f32x4 __attribute__((ext_vector_type(4)));
using bf16 = __hip_bfloat16;

// async global->LDS, 16B per lane; LDS dst = base + lane*16 (wave-uniform base)
#define ASYNC16(gp, lp) __builtin_amdgcn_global_load_lds( \
    (__attribute__((address_space(1))) void*)(void*)(gp), \
    (__attribute__((address_space(3))) void*)(void*)(lp), 16, 0, 0)

// ---------------- fused prep: x->bf16, weights->bf16, rope tables ----------------
__global__ __launch_bounds__(256) void prep_kernel(const float* __restrict__ x, const float* __restrict__ Wq,
                                                   const float* __restrict__ Wk, const float* __restrict__ Wv,
                                                   const float* __restrict__ Wo, bf16* __restrict__ xb,
                                                   bf16* __restrict__ wqkv, bf16* __restrict__ wo,
                                                   float* __restrict__ cosd, float* __restrict__ sind) {
    int bid = blockIdx.x;
    if (bid < 16384) {  // x convert: 16,777,216 elems
        size_t i = ((size_t)bid * 256 + threadIdx.x) * 4;
        const float4 f = *(const float4*)(x + i);
        bf16 t[4];
        t[0] = __float2bfloat16(f.x); t[1] = __float2bfloat16(f.y);
        t[2] = __float2bfloat16(f.z); t[3] = __float2bfloat16(f.w);
        *(uint2*)(xb + i) = *(const uint2*)t;
    } else if (bid < 18944) {  // weights: Wq|Wk|Wv -> wqkv, Wo -> wo
        size_t e = ((size_t)(bid - 16384) * 256 + threadIdx.x) * 4;
        const float* src;
        bf16* dst;
        if (e < 1048576)        { src = Wq + e;             dst = wqkv + e; }
        else if (e < 1310720)   { src = Wk + (e - 1048576); dst = wqkv + e; }
        else if (e < 1572864)   { src = Wv + (e - 1310720); dst = wqkv + e; }
        else                    { src = Wo + (e - 1572864); dst = wo + (e - 1572864); }
        const float4 f = *(const float4*)src;
        bf16 t[4];
        t[0] = __float2bfloat16(f.x); t[1] = __float2bfloat16(f.y);
        t[2] = __float2bfloat16(f.z); t[3] = __float2bfloat16(f.w);
        *(uint2*)dst = *(const uint2*)t;
    } else {  // rope tables: S_*32 entries, f64 range-reduction + hw sin/cos
        int idx = (bid - 18944) * 256 + threadIdx.x;
        int s = idx >> 5, i = idx & 31;
        double inv = exp((double)i * (-9.210340371976184 / 32.0));  // 10000^(-i/32)
        double rev = ((double)s * inv) * 0.15915494309189535;       // angle / 2pi
        double frac = rev - floor(rev);
        float a = (float)frac * 6.2831853071795865f;
        cosd[idx] = __cosf(a);
        sind[idx] = __sinf(a);
    }
}

// ---------------- C[M][N] = A[M][K]*B[N][K]^T, bf16 in, OT out ----------------
// R2 decision: 128^2 m97-structure is the keeper. 8-phase 256^2 measured 715 TF here
// (2-phase level; K=1024 too short to amortize -- m248's full-stack = 848 TF at this K),
// vs this kernel's proven 876 TF at 3 blocks/CU. Do not revisit without new evidence.
// grid (M/128, N/128): x = M-tile so blocks sharing an A-tile have equal id%8 (same XCD).
// Columns < rope_ncols get RoPE applied in the epilogue (wave-uniform: 64-col strips).
template <typename OT>
__global__ __launch_bounds__(256, 3) void gemm_bt_kernel(const bf16* __restrict__ A, const bf16* __restrict__ Bm,
                                                         OT* __restrict__ C, int M, int N, int K, int rope_ncols,
                                                         const float* __restrict__ cosd,
                                                         const float* __restrict__ sind) {
    __shared__ bf16 As[128 * 64];
    __shared__ bf16 Bs[128 * 64];
    const int tid = threadIdx.x;
    const int bm = blockIdx.x * 128, bn = blockIdx.y * 128;
    const int wave = tid >> 6, lane = tid & 63;
    const int wm = (wave >> 1) * 64, wn = (wave & 1) * 64;
    const int lr = lane & 15, quad = lane >> 4;
    const int srow = wave * 32;
    const int lrow = lane >> 3;                        // 0..7
    const int lchunk = ((lane & 7) ^ lrow) * 8;        // XOR-swizzled source chunk (elems)
    const bf16* Ag = A + (size_t)(bm + srow + lrow) * K + lchunk;
    const bf16* Bg = Bm + (size_t)(bn + srow + lrow) * K + lchunk;
    f32x4 acc[4][4] = {};
    for (int k0 = 0; k0 < K; k0 += 64) {
#pragma unroll
        for (int p = 0; p < 4; ++p) {
            ASYNC16(Ag + (size_t)(p * 8) * K + k0, &As[(srow + p * 8) * 64]);
            ASYNC16(Bg + (size_t)(p * 8) * K + k0, &Bs[(srow + p * 8) * 64]);
        }
        __syncthreads();
#pragma unroll
        for (int kk = 0; kk < 64; kk += 32) {
            const int sw = (((kk >> 3) + quad) ^ (lr & 7)) << 3;  // de-swizzled chunk offset
            bf16x8 af[4], bfr[4];
#pragma unroll
            for (int i = 0; i < 4; ++i) af[i] = *(const bf16x8*)(&As[(wm + i * 16 + lr) * 64 + sw]);
#pragma unroll
            for (int i = 0; i < 4; ++i) bfr[i] = *(const bf16x8*)(&Bs[(wn + i * 16 + lr) * 64 + sw]);
#pragma unroll
            for (int mi = 0; mi < 4; ++mi)
#pragma unroll
                for (int ni = 0; ni < 4; ++ni)
                    acc[mi][ni] = __builtin_amdgcn_mfma_f32_16x16x32_bf16(af[mi], bfr[ni], acc[mi][ni], 0, 0, 0);
        }
        __syncthreads();
    }
    if (bn + wn < rope_ncols) {
        // wave's 64 columns = exactly one head; pair (i, i+32) = (acc[mi][ni], acc[mi][ni+2])
#pragma unroll
        for (int mi = 0; mi < 4; ++mi)
#pragma unroll
            for (int r = 0; r < 4; ++r) {
                int row = bm + wm + mi * 16 + quad * 4 + r;
                int s = row & (S_ - 1);
#pragma unroll
                for (int ni = 0; ni < 2; ++ni) {
                    int i = ni * 16 + lr;
                    float cs = cosd[(s << 5) + i];
                    float sn = sind[(s << 5) + i];
                    float x1 = acc[mi][ni][r], x2 = acc[mi][ni + 2][r];
                    acc[mi][ni][r] = x1 * cs - x2 * sn;
                    acc[mi][ni + 2][r] = x2 * cs + x1 * sn;
                }
            }
    }
#pragma unroll
    for (int mi = 0; mi < 4; ++mi)
#pragma unroll
        for (int ni = 0; ni < 4; ++ni)
#pragma unroll
            for (int r = 0; r < 4; ++r) {
                int row = bm + wm + mi * 16 + quad * 4 + r;
                int col = bn + wn + ni * 16 + lr;
                float v = acc[mi][ni][r];
                if constexpr (__is_same(OT, float)) C[(size_t)row * N + col] = v;
                else C[(size_t)row * N + col] = __float2bfloat16(v);
            }
}

// XOR chunk swizzle for transposed LDS tiles (row stride 136 elems, b128-aligned):
// element (row e, col t): addr = e*136 + ((chunk & ~7)<<3) + (((chunk ^ (e>>3)) & 7)<<3) + (t&7),
// chunk = t>>3. Bit 3 of chunk MUST be kept (cols 0..127 -> chunk 0..15); dropping it
// aliases t and t+64 (the R4 NaN bug). Transpose stores hit 8 distinct banks; b128 reads aligned.

// ---------------- per-chunk KV contribution, PER-GROUP: all 4 heads of group g ----------------
// C_h[e][d] = sum_t v[t][e]*kdec_h[t]*k[t][d]. kdec multiplies along the MFMA K-dim (t), so it
// attaches to EITHER operand; moving it to the v-side A-frag lets k/v be staged RAW and ONCE
// per group (was 4x redundant per-head staging). 512 thr = 8 waves: wave w -> e-block
// (w&3)*16, head-pair (w>>2)*2. A-frag t-mapping: frag at chunk qa holds t = qa*8 + i
// (i=0..7), qa = (ks>>3)+quad -> kdec(t) = exp(-slope*(127-ks-quad*8)) * exp(slope)^i,
// applied as serial multiply chain in f32, rounded to bf16 (same rounding class as the old
// k-side bf16 product). LDS 34.8 KB -> 4 blocks/CU (32 waves).
__global__ __launch_bounds__(512) void chunk_kv_kernel(const bf16* __restrict__ qkv, bf16* __restrict__ Cout) {
    const int j = blockIdx.x, g = blockIdx.y, b = blockIdx.z;
    __shared__ bf16 kT[64 * 136];
    __shared__ bf16 vT[64 * 136];
    const int tid = threadIdx.x;
#pragma unroll
    for (int p = 0; p < 2; ++p) {
        int flat = p * 512 + tid;
        int t = flat >> 3, d0 = (flat & 7) * 8;
        const size_t row = (size_t)(b * S_ + j * 128 + t);
        uint4 kw = *(const uint4*)(qkv + row * 1536 + 1024 + g * 64 + d0);
        uint4 vw = *(const uint4*)(qkv + row * 1536 + 1280 + g * 64 + d0);
        const bf16* kp = (const bf16*)&kw;
        const bf16* vp = (const bf16*)&vw;
#pragma unroll
        for (int i = 0; i < 8; ++i) {
            int e = d0 + i;
            int sw = (((t >> 3) & ~7) << 3) + ((((t >> 3) ^ (e >> 3)) & 7) << 3) + (t & 7);
            kT[e * 136 + sw] = kp[i];
            vT[e * 136 + sw] = vp[i];
        }
    }
    __syncthreads();
    const int wave = tid >> 6, lane = tid & 63, lr = lane & 15, quad = lane >> 4;
    const int eblk = (wave & 3) * 16;
    const int hp = (wave >> 2) * 2;   // heads g*4+hp, g*4+hp+1
    f32x4 acc[2][4] = {};
    float slope[2], g1[2];
#pragma unroll
    for (int hh = 0; hh < 2; ++hh) {
        slope[hh] = exp2f(-0.5f * (float)(g * 4 + hp + hh + 1));
        g1[hh] = __expf(slope[hh]);
    }
#pragma unroll
    for (int ks = 0; ks < 128; ks += 32) {
        int qa = (ks >> 3) + quad;
        int qhi = (qa & ~7) << 3;
        int ea = eblk + lr;
        bf16x8 a = *(const bf16x8*)(&vT[ea * 136 + qhi + (((qa ^ (ea >> 3)) & 7) << 3)]);
        float av[8];
#pragma unroll
        for (int i = 0; i < 8; ++i) av[i] = (float)a[i];
        bf16x8 bb[4];
#pragma unroll
        for (int ni = 0; ni < 4; ++ni) {
            int eb = ni * 16 + lr;
            bb[ni] = *(const bf16x8*)(&kT[eb * 136 + qhi + (((qa ^ (eb >> 3)) & 7) << 3)]);
        }
#pragma unroll
        for (int hh = 0; hh < 2; ++hh) {
            float m = __expf(-slope[hh] * (float)(127 - ks - quad * 8));
            bf16x8 as;
#pragma unroll
            for (int i = 0; i < 8; ++i) { as[i] = (__bf16)(av[i] * m); m *= g1[hh]; }
#pragma unroll
            for (int ni = 0; ni < 4; ++ni)
                acc[hh][ni] = __builtin_amdgcn_mfma_f32_16x16x32_bf16(as, bb[ni], acc[hh][ni], 0, 0, 0);
        }
    }
#pragma unroll
    for (int hh = 0; hh < 2; ++hh) {
        int h = g * 4 + hp + hh;
        bf16* out = Cout + ((size_t)((b * NH_ + h) * NC_ + j)) * 4096;
#pragma unroll
        for (int ni = 0; ni < 4; ++ni)
#pragma unroll
            for (int r = 0; r < 4; ++r)
                out[(eblk + quad * 4 + r) * 64 + ni * 16 + lr] = __float2bfloat16(acc[hh][ni][r]);
    }
}

// ---------------- exclusive decay scan: one (bh,e,d) lane per thread, coalesced ----------------
__global__ __launch_bounds__(256) void scan_kv_kernel(const bf16* __restrict__ Cin, bf16* __restrict__ st) {
    const int bh = blockIdx.x >> 4;                       // 16 blocks per bh
    const int f = ((blockIdx.x & 15) << 8) + threadIdx.x; // 0..4095
    const int h = bh & (NH_ - 1);
    const float slope = exp2f(-0.5f * (float)(h + 1));
    const float bdec = __expf(-slope * 128.0f);
    const bf16* Cb = Cin + (size_t)bh * NC_ * 4096 + f;
    bf16* sb = st + (size_t)bh * NC_ * 4096 + f;
    float carry = 0.f;
#pragma unroll 8
    for (int c = 0; c < NC_; ++c) {
        sb[(size_t)c * 4096] = __float2bfloat16(carry);
        carry = bdec * carry + __bfloat162float(Cb[(size_t)c * 4096]);
    }
}

// ---------------- per-chunk output: O = (mask ∘ qk^T) v + (q*qdec) kv ----------------
// R4 post-mortem: 512-thr/8-wave variant REGRESSED (262->280). Block-level TLP (3 blocks/CU
// of 256 thr) is what hides the barrier-serialized phase chain; do not trade it away.
// This is R3's 4-wave geometry + two unbundled micro-opts:
//  (1) q-frags cached in regs across QK^T and qKV (saves 4 LDS reads/wave + dependency),
//  (2) T14 early-issue: v-tile uint4 loads at kernel top, LDS scatter-write in phase 3.
// q/k staged via chunk-XOR pre-swizzled ASYNC16 into linear [128][64] tiles. Read addr:
// [t*64 + ((chunk ^ (t&7))<<3)], chunk = (kk>>3)+quad; all read sites have t&7 == lr&7.
// LDS overlay: phase1 {qs[128][64], kbs[128][64]}; phase2 {Ps[128][136], vT[64][136]}.
// Union 26112 elems = 52.2 KB -> 3 blocks/CU.
__global__ __launch_bounds__(256, 3) void attn_chunk_kernel(const bf16* __restrict__ qkv,
                                                            const bf16* __restrict__ kvst,
                                                            bf16* __restrict__ outb) {
    const int c = blockIdx.x, h = blockIdx.y, b = blockIdx.z;
    const int g = h >> 2;
    const float slope = exp2f(-0.5f * (float)(h + 1));
    __shared__ bf16 smem[26112];
    bf16* qs  = smem;            // phase1: [128][64] chunk-XOR swizzled
    bf16* kbs = smem + 8192;     // phase1: [128][64] chunk-XOR swizzled
    bf16* Ps  = smem;            // phase2: [128][136] swizzled
    bf16* vT  = smem + 17408;    // phase2: [64][136] swizzled
    const int tid = threadIdx.x;
    const int wave = tid >> 6, lane = tid & 63, lr = lane & 15, quad = lane >> 4;
    const int srow = lane >> 3;                  // 0..7
    const int schunk = ((lane & 7) ^ srow) * 8;  // pre-swizzled source chunk (elems)
    // T14 early-issue: v-tile loads at top; land during QK^T/qKV; LDS-written in phase 3
    uint4 vreg[4];
#pragma unroll
    for (int p = 0; p < 4; ++p) {
        int flat = p * 256 + tid;
        int t = flat >> 3, d0 = (flat & 7) * 8;
        size_t row = (size_t)(b * S_ + c * 128 + t);
        vreg[p] = *(const uint4*)(qkv + row * 1536 + 1280 + g * 64 + d0);
    }
#pragma unroll
    for (int p = 0; p < 4; ++p) {
        int t0 = wave * 8 + p * 32;
        size_t row = (size_t)(b * S_ + c * 128 + t0 + srow);
        ASYNC16(qkv + row * 1536 + h * 64 + schunk, &qs[t0 * 64]);
        ASYNC16(qkv + row * 1536 + 1024 + g * 64 + schunk, &kbs[t0 * 64]);
    }
    asm volatile("s_waitcnt vmcnt(0)");
    __syncthreads();
    const int m0 = wave * 32;
    // q-frags cached: rows m0+lr and m0+16+lr, chunk (kk>>3)+quad (reused by qKV term)
    bf16x8 qf0[2], qf1[2];
#pragma unroll
    for (int kk = 0; kk < 2; ++kk) {
        const int sw = (((kk * 4 + quad) ^ (lr & 7)) & 7) << 3;
        qf0[kk] = *(const bf16x8*)(&qs[(m0 + lr) * 64 + sw]);
        qf1[kk] = *(const bf16x8*)(&qs[(m0 + 16 + lr) * 64 + sw]);
    }
    f32x4 sacc[2][8] = {};
#pragma unroll
    for (int kk = 0; kk < 2; ++kk) {
        const int sw = (((kk * 4 + quad) ^ (lr & 7)) & 7) << 3;
#pragma unroll
        for (int ni = 0; ni < 8; ++ni) {
            bf16x8 bfr = *(const bf16x8*)(&kbs[(ni * 16 + lr) * 64 + sw]);
            sacc[0][ni] = __builtin_amdgcn_mfma_f32_16x16x32_bf16(qf0[kk], bfr, sacc[0][ni], 0, 0, 0);
            sacc[1][ni] = __builtin_amdgcn_mfma_f32_16x16x32_bf16(qf1[kk], bfr, sacc[1][ni], 0, 0, 0);
        }
    }
    // qKV term from scanned state (global, L2-resident); q from cached frags
    f32x4 oacc[2][4] = {};
    const bf16* kvb = kvst + ((size_t)((b * NH_ + h) * NC_ + c)) * 4096;
    float qd0 = __expf(-slope * (float)(m0 + lr + 1));
    float qd1 = __expf(-slope * (float)(m0 + 16 + lr + 1));
#pragma unroll
    for (int kk = 0; kk < 2; ++kk) {
        bf16x8 a0, a1;
#pragma unroll
        for (int i = 0; i < 8; ++i) {
            a0[i] = (__bf16)((float)qf0[kk][i] * qd0);
            a1[i] = (__bf16)((float)qf1[kk][i] * qd1);
        }
#pragma unroll
        for (int ni = 0; ni < 4; ++ni) {
            bf16x8 bk = *(const bf16x8*)(kvb + (ni * 16 + lr) * 64 + kk * 32 + quad * 8);
            oacc[0][ni] = __builtin_amdgcn_mfma_f32_16x16x32_bf16(a0, bk, oacc[0][ni], 0, 0, 0);
            oacc[1][ni] = __builtin_amdgcn_mfma_f32_16x16x32_bf16(a1, bk, oacc[1][ni], 0, 0, 0);
        }
    }
    __syncthreads();  // qs/kbs fully consumed; region reused for Ps/vT
    // factorized mask: exp(-s*(t-tp)) = exp(-s*(t-m0)) * exp(-s*max(m0-tp,-31))
    float ftv[2][4], gtv[8];
#pragma unroll
    for (int mi = 0; mi < 2; ++mi)
#pragma unroll
        for (int r = 0; r < 4; ++r) ftv[mi][r] = __expf(-slope * (float)(mi * 16 + quad * 4 + r));
#pragma unroll
    for (int ni = 0; ni < 8; ++ni)
        gtv[ni] = __expf(-slope * fmaxf((float)(m0 - (ni * 16 + lr)), -31.0f));
#pragma unroll
    for (int mi = 0; mi < 2; ++mi)
#pragma unroll
        for (int ni = 0; ni < 8; ++ni)
#pragma unroll
            for (int r = 0; r < 4; ++r) {
                int t = m0 + mi * 16 + quad * 4 + r;
                int tp = ni * 16 + lr;
                float val = (t >= tp) ? sacc[mi][ni][r] * ftv[mi][r] * gtv[ni] : 0.f;
                int sw = (((tp >> 3) & ~7) << 3) + ((((tp >> 3) ^ (t >> 3)) & 7) << 3) + (tp & 7);
                Ps[t * 136 + sw] = __float2bfloat16(val);
            }
    // write v transposed (swizzled) from the early-issued regs
#pragma unroll
    for (int p = 0; p < 4; ++p) {
        int flat = p * 256 + tid;
        int t = flat >> 3, d0 = (flat & 7) * 8;
        const bf16* vp = (const bf16*)&vreg[p];
#pragma unroll
        for (int i = 0; i < 8; ++i) {
            int e = d0 + i;
            int sw = (((t >> 3) & ~7) << 3) + ((((t >> 3) ^ (e >> 3)) & 7) << 3) + (t & 7);
            vT[e * 136 + sw] = vp[i];
        }
    }
    __syncthreads();
#pragma unroll
    for (int ks2 = 0; ks2 < 128; ks2 += 32) {
        int qa = (ks2 >> 3) + quad;             // chunk index 0..15
        int qhi = (qa & ~7) << 3;
        int ra0 = m0 + lr, ra1 = m0 + 16 + lr;
        bf16x8 af0 = *(const bf16x8*)(&Ps[ra0 * 136 + qhi + (((qa ^ (ra0 >> 3)) & 7) << 3)]);
        bf16x8 af1 = *(const bf16x8*)(&Ps[ra1 * 136 + qhi + (((qa ^ (ra1 >> 3)) & 7) << 3)]);
#pragma unroll
        for (int ni = 0; ni < 4; ++ni) {
            int eb = ni * 16 + lr;
            bf16x8 bfv = *(const bf16x8*)(&vT[eb * 136 + qhi + (((qa ^ (eb >> 3)) & 7) << 3)]);
            oacc[0][ni] = __builtin_amdgcn_mfma_f32_16x16x32_bf16(af0, bfv, oacc[0][ni], 0, 0, 0);
            oacc[1][ni] = __builtin_amdgcn_mfma_f32_16x16x32_bf16(af1, bfv, oacc[1][ni], 0, 0, 0);
        }
    }
#pragma unroll
    for (int mi = 0; mi < 2; ++mi)
#pragma unroll
        for (int ni = 0; ni < 4; ++ni)
#pragma unroll
            for (int r = 0; r < 4; ++r) {
                int t = m0 + mi * 16 + quad * 4 + r;
                int e = ni * 16 + lr;
                size_t row = (size_t)(b * S_ + c * 128 + t);
                outb[row * (NH_ * 64) + h * 64 + e] = __float2bfloat16(oacc[mi][ni][r]);
            }
}

extern "C" void kernel_launch(void* const* d_in, const int* in_sizes, int n_in,
                              void* d_out, int out_size, void* d_ws, size_t ws_size,
                              hipStream_t stream) {
    (void)in_sizes; (void)n_in; (void)out_size; (void)ws_size;
    const float* x  = (const float*)d_in[0];
    const float* Wq = (const float*)d_in[1];
    const float* Wk = (const float*)d_in[2];
    const float* Wv = (const float*)d_in[3];
    const float* Wo = (const float*)d_in[4];
    float* out = (float*)d_out;
    char* ws = (char*)d_ws;
    bf16*  xb    = (bf16*)(ws);                    // 33,554,432 (reused as attn_out)
    bf16*  qkvb  = (bf16*)(ws + 33554432);         // 50,331,648  [M][1536]: q|k|v
    bf16*  wqkvb = (bf16*)(ws + 83886080);         //  3,145,728  [1536][1024]
    bf16*  wob   = (bf16*)(ws + 87031808);         //  2,097,152
    float* cosd  = (float*)(ws + 89128960);        //  1,048,576
    float* sind  = (float*)(ws + 90177536);        //  1,048,576
    bf16*  Cbuf  = (bf16*)(ws + 91226112);         // 16,777,216
    bf16*  kvst  = (bf16*)(ws + 108003328);        // 16,777,216  -> total 124,780,544 B
    bf16*  attn  = xb;

    prep_kernel<<<19968, 256, 0, stream>>>(x, Wq, Wk, Wv, Wo, xb, wqkvb, wob, cosd, sind);

    // fused q|k|v projection with RoPE on cols < 1280 (q heads + k heads)
    gemm_bt_kernel<bf16><<<dim3(128, 12), 256, 0, stream>>>(xb, wqkvb, qkvb, 16384, 1536, 1024, 1280, cosd, sind);

    // per-GROUP chunk KV (4 heads/block, raw k/v staged once)
    chunk_kv_kernel<<<dim3(NC_, NKV_, B_), 512, 0, stream>>>(qkvb, Cbuf);
    scan_kv_kernel<<<512, 256, 0, stream>>>(Cbuf, kvst);
    attn_chunk_kernel<<<dim3(NC_, NH_, B_), 256, 0, stream>>>(qkvb, kvst, attn);

    gemm_bt_kernel<float><<<dim3(128, 8), 256, 0, stream>>>(attn, wob, out, 16384, 1024, 1024, 0, cosd, sind);
}

// Round 6
// 264.447 us; speedup vs baseline: 1.0587x; 1.0274x over previous
//
#include <hip/hip_runtime.h>
#include <hip/hip_bf16.h>

#define B_ 2
#define S_ 8192
#define DIM_ 1024
#define NH_ 16
#define NKV_ 4
#define HD_ 64
#define NC_ 64

typedef __bf16 bf16x8 __attribute__((ext_vector_type(8)));
typedef float f32x4 __attribute__((ext_vector_type(4)));
using bf16 = __hip_bfloat16;

// async global->LDS, 16B per lane; LDS dst = base + lane*16 (wave-uniform base)
#define ASYNC16(gp, lp) __builtin_amdgcn_global_load_lds( \
    (__attribute__((address_space(1))) void*)(void*)(gp), \
    (__attribute__((address_space(3))) void*)(void*)(lp), 16, 0, 0)

// ---------------- fused prep: x->bf16, weights->bf16, rope tables ----------------
__global__ __launch_bounds__(256) void prep_kernel(const float* __restrict__ x, const float* __restrict__ Wq,
                                                   const float* __restrict__ Wk, const float* __restrict__ Wv,
                                                   const float* __restrict__ Wo, bf16* __restrict__ xb,
                                                   bf16* __restrict__ wqkv, bf16* __restrict__ wo,
                                                   float* __restrict__ cosd, float* __restrict__ sind) {
    int bid = blockIdx.x;
    if (bid < 16384) {  // x convert: 16,777,216 elems
        size_t i = ((size_t)bid * 256 + threadIdx.x) * 4;
        const float4 f = *(const float4*)(x + i);
        bf16 t[4];
        t[0] = __float2bfloat16(f.x); t[1] = __float2bfloat16(f.y);
        t[2] = __float2bfloat16(f.z); t[3] = __float2bfloat16(f.w);
        *(uint2*)(xb + i) = *(const uint2*)t;
    } else if (bid < 18944) {  // weights: Wq|Wk|Wv -> wqkv, Wo -> wo
        size_t e = ((size_t)(bid - 16384) * 256 + threadIdx.x) * 4;
        const float* src;
        bf16* dst;
        if (e < 1048576)        { src = Wq + e;             dst = wqkv + e; }
        else if (e < 1310720)   { src = Wk + (e - 1048576); dst = wqkv + e; }
        else if (e < 1572864)   { src = Wv + (e - 1310720); dst = wqkv + e; }
        else                    { src = Wo + (e - 1572864); dst = wo + (e - 1572864); }
        const float4 f = *(const float4*)src;
        bf16 t[4];
        t[0] = __float2bfloat16(f.x); t[1] = __float2bfloat16(f.y);
        t[2] = __float2bfloat16(f.z); t[3] = __float2bfloat16(f.w);
        *(uint2*)dst = *(const uint2*)t;
    } else {  // rope tables: S_*32 entries, f64 range-reduction + hw sin/cos
        int idx = (bid - 18944) * 256 + threadIdx.x;
        int s = idx >> 5, i = idx & 31;
        double inv = exp((double)i * (-9.210340371976184 / 32.0));  // 10000^(-i/32)
        double rev = ((double)s * inv) * 0.15915494309189535;       // angle / 2pi
        double frac = rev - floor(rev);
        float a = (float)frac * 6.2831853071795865f;
        cosd[idx] = __cosf(a);
        sind[idx] = __sinf(a);
    }
}

// ---------------- C[M][N] = A[M][K]*B[N][K]^T, bf16 in, OT out ----------------
// R2 decision: 128^2 m97-structure is the keeper (876 TF @ 3 blocks/CU); 8-phase 256^2
// measured 715 TF here. Do not revisit without new evidence.
// R6: MINW template param. Grid-tail rule: at MINW blocks/CU there are 256*MINW concurrent
// slots; grid must divide evenly or the last partial round costs a FULL round (gemm2 at
// 3/CU: 1024/768 = 1.33 rounds -> measured SAME 58.5us as gemm1's 2.0 rounds, 588 vs 876 TF).
// gemm1: 1536 blocks @ MINW=3 (768 slots, 2.0 exact). gemm2: 1024 blocks @ MINW=4 (1024
// slots, 1.0 exact; LDS 32KB*4=128<=160KB, VGPR 64 -> fits).
// grid (M/128, N/128): x = M-tile so blocks sharing an A-tile have equal id%8 (same XCD).
// Columns < rope_ncols get RoPE applied in the epilogue (wave-uniform: 64-col strips).
template <typename OT, int MINW>
__global__ __launch_bounds__(256, MINW) void gemm_bt_kernel(const bf16* __restrict__ A, const bf16* __restrict__ Bm,
                                                            OT* __restrict__ C, int M, int N, int K, int rope_ncols,
                                                            const float* __restrict__ cosd,
                                                            const float* __restrict__ sind) {
    __shared__ bf16 As[128 * 64];
    __shared__ bf16 Bs[128 * 64];
    const int tid = threadIdx.x;
    const int bm = blockIdx.x * 128, bn = blockIdx.y * 128;
    const int wave = tid >> 6, lane = tid & 63;
    const int wm = (wave >> 1) * 64, wn = (wave & 1) * 64;
    const int lr = lane & 15, quad = lane >> 4;
    const int srow = wave * 32;
    const int lrow = lane >> 3;                        // 0..7
    const int lchunk = ((lane & 7) ^ lrow) * 8;        // XOR-swizzled source chunk (elems)
    const bf16* Ag = A + (size_t)(bm + srow + lrow) * K + lchunk;
    const bf16* Bg = Bm + (size_t)(bn + srow + lrow) * K + lchunk;
    f32x4 acc[4][4] = {};
    for (int k0 = 0; k0 < K; k0 += 64) {
#pragma unroll
        for (int p = 0; p < 4; ++p) {
            ASYNC16(Ag + (size_t)(p * 8) * K + k0, &As[(srow + p * 8) * 64]);
            ASYNC16(Bg + (size_t)(p * 8) * K + k0, &Bs[(srow + p * 8) * 64]);
        }
        __syncthreads();
#pragma unroll
        for (int kk = 0; kk < 64; kk += 32) {
            const int sw = (((kk >> 3) + quad) ^ (lr & 7)) << 3;  // de-swizzled chunk offset
            bf16x8 af[4], bfr[4];
#pragma unroll
            for (int i = 0; i < 4; ++i) af[i] = *(const bf16x8*)(&As[(wm + i * 16 + lr) * 64 + sw]);
#pragma unroll
            for (int i = 0; i < 4; ++i) bfr[i] = *(const bf16x8*)(&Bs[(wn + i * 16 + lr) * 64 + sw]);
#pragma unroll
            for (int mi = 0; mi < 4; ++mi)
#pragma unroll
                for (int ni = 0; ni < 4; ++ni)
                    acc[mi][ni] = __builtin_amdgcn_mfma_f32_16x16x32_bf16(af[mi], bfr[ni], acc[mi][ni], 0, 0, 0);
        }
        __syncthreads();
    }
    if (bn + wn < rope_ncols) {
        // wave's 64 columns = exactly one head; pair (i, i+32) = (acc[mi][ni], acc[mi][ni+2])
#pragma unroll
        for (int mi = 0; mi < 4; ++mi)
#pragma unroll
            for (int r = 0; r < 4; ++r) {
                int row = bm + wm + mi * 16 + quad * 4 + r;
                int s = row & (S_ - 1);
#pragma unroll
                for (int ni = 0; ni < 2; ++ni) {
                    int i = ni * 16 + lr;
                    float cs = cosd[(s << 5) + i];
                    float sn = sind[(s << 5) + i];
                    float x1 = acc[mi][ni][r], x2 = acc[mi][ni + 2][r];
                    acc[mi][ni][r] = x1 * cs - x2 * sn;
                    acc[mi][ni + 2][r] = x2 * cs + x1 * sn;
                }
            }
    }
#pragma unroll
    for (int mi = 0; mi < 4; ++mi)
#pragma unroll
        for (int ni = 0; ni < 4; ++ni)
#pragma unroll
            for (int r = 0; r < 4; ++r) {
                int row = bm + wm + mi * 16 + quad * 4 + r;
                int col = bn + wn + ni * 16 + lr;
                float v = acc[mi][ni][r];
                if constexpr (__is_same(OT, float)) C[(size_t)row * N + col] = v;
                else C[(size_t)row * N + col] = __float2bfloat16(v);
            }
}

// XOR chunk swizzle for transposed LDS tiles (row stride 136 elems, b128-aligned):
// element (row e, col t): addr = e*136 + ((chunk & ~7)<<3) + (((chunk ^ (e>>3)) & 7)<<3) + (t&7),
// chunk = t>>3. Bit 3 of chunk MUST be kept (cols 0..127 -> chunk 0..15); dropping it
// aliases t and t+64 (the R4 NaN bug). Transpose stores hit 8 distinct banks; b128 reads aligned.

// ---------------- per-chunk KV contribution, PER-GROUP: all 4 heads of group g ----------------
// C_h[e][d] = sum_t v[t][e]*kdec_h[t]*k[t][d]. kdec multiplies along the MFMA K-dim (t), so it
// attaches to EITHER operand; moving it to the v-side A-frag lets k/v be staged RAW and ONCE
// per group (was 4x redundant per-head staging). 512 thr = 8 waves: wave w -> e-block
// (w&3)*16, head-pair (w>>2)*2. A-frag t-mapping: frag at chunk qa holds t = qa*8 + i
// (i=0..7), qa = (ks>>3)+quad -> kdec(t) = exp(-slope*(127-ks-quad*8)) * exp(slope)^i,
// applied as serial multiply chain in f32, rounded to bf16 (same rounding class as the old
// k-side bf16 product). LDS 34.8 KB -> 4 blocks/CU (32 waves).
__global__ __launch_bounds__(512) void chunk_kv_kernel(const bf16* __restrict__ qkv, bf16* __restrict__ Cout) {
    const int j = blockIdx.x, g = blockIdx.y, b = blockIdx.z;
    __shared__ bf16 kT[64 * 136];
    __shared__ bf16 vT[64 * 136];
    const int tid = threadIdx.x;
#pragma unroll
    for (int p = 0; p < 2; ++p) {
        int flat = p * 512 + tid;
        int t = flat >> 3, d0 = (flat & 7) * 8;
        const size_t row = (size_t)(b * S_ + j * 128 + t);
        uint4 kw = *(const uint4*)(qkv + row * 1536 + 1024 + g * 64 + d0);
        uint4 vw = *(const uint4*)(qkv + row * 1536 + 1280 + g * 64 + d0);
        const bf16* kp = (const bf16*)&kw;
        const bf16* vp = (const bf16*)&vw;
#pragma unroll
        for (int i = 0; i < 8; ++i) {
            int e = d0 + i;
            int sw = (((t >> 3) & ~7) << 3) + ((((t >> 3) ^ (e >> 3)) & 7) << 3) + (t & 7);
            kT[e * 136 + sw] = kp[i];
            vT[e * 136 + sw] = vp[i];
        }
    }
    __syncthreads();
    const int wave = tid >> 6, lane = tid & 63, lr = lane & 15, quad = lane >> 4;
    const int eblk = (wave & 3) * 16;
    const int hp = (wave >> 2) * 2;   // heads g*4+hp, g*4+hp+1
    f32x4 acc[2][4] = {};
    float slope[2], g1[2];
#pragma unroll
    for (int hh = 0; hh < 2; ++hh) {
        slope[hh] = exp2f(-0.5f * (float)(g * 4 + hp + hh + 1));
        g1[hh] = __expf(slope[hh]);
    }
#pragma unroll
    for (int ks = 0; ks < 128; ks += 32) {
        int qa = (ks >> 3) + quad;
        int qhi = (qa & ~7) << 3;
        int ea = eblk + lr;
        bf16x8 a = *(const bf16x8*)(&vT[ea * 136 + qhi + (((qa ^ (ea >> 3)) & 7) << 3)]);
        float av[8];
#pragma unroll
        for (int i = 0; i < 8; ++i) av[i] = (float)a[i];
        bf16x8 bb[4];
#pragma unroll
        for (int ni = 0; ni < 4; ++ni) {
            int eb = ni * 16 + lr;
            bb[ni] = *(const bf16x8*)(&kT[eb * 136 + qhi + (((qa ^ (eb >> 3)) & 7) << 3)]);
        }
#pragma unroll
        for (int hh = 0; hh < 2; ++hh) {
            float m = __expf(-slope[hh] * (float)(127 - ks - quad * 8));
            bf16x8 as;
#pragma unroll
            for (int i = 0; i < 8; ++i) { as[i] = (__bf16)(av[i] * m); m *= g1[hh]; }
#pragma unroll
            for (int ni = 0; ni < 4; ++ni)
                acc[hh][ni] = __builtin_amdgcn_mfma_f32_16x16x32_bf16(as, bb[ni], acc[hh][ni], 0, 0, 0);
        }
    }
#pragma unroll
    for (int hh = 0; hh < 2; ++hh) {
        int h = g * 4 + hp + hh;
        bf16* out = Cout + ((size_t)((b * NH_ + h) * NC_ + j)) * 4096;
#pragma unroll
        for (int ni = 0; ni < 4; ++ni)
#pragma unroll
            for (int r = 0; r < 4; ++r)
                out[(eblk + quad * 4 + r) * 64 + ni * 16 + lr] = __float2bfloat16(acc[hh][ni][r]);
    }
}

// ---------------- exclusive decay scan: one (bh,e,d) lane per thread, coalesced ----------------
__global__ __launch_bounds__(256) void scan_kv_kernel(const bf16* __restrict__ Cin, bf16* __restrict__ st) {
    const int bh = blockIdx.x >> 4;                       // 16 blocks per bh
    const int f = ((blockIdx.x & 15) << 8) + threadIdx.x; // 0..4095
    const int h = bh & (NH_ - 1);
    const float slope = exp2f(-0.5f * (float)(h + 1));
    const float bdec = __expf(-slope * 128.0f);
    const bf16* Cb = Cin + (size_t)bh * NC_ * 4096 + f;
    bf16* sb = st + (size_t)bh * NC_ * 4096 + f;
    float carry = 0.f;
#pragma unroll 8
    for (int c = 0; c < NC_; ++c) {
        sb[(size_t)c * 4096] = __float2bfloat16(carry);
        carry = bdec * carry + __bfloat162float(Cb[(size_t)c * 4096]);
    }
}

// ---------------- per-chunk output: O = (mask ∘ qk^T) v + (q*qdec) kv ----------------
// EXACT R3 config (best measured: 261.7us total). R4 (8-wave) and R5 (reg-cached q + early-v)
// both regressed: block-level TLP (3 blocks/CU) hides the barrier chain, and any added
// register pressure in this kernel costs more than the LDS traffic it saves. Do not add
// live-range across phases.
// q/k staged via chunk-XOR pre-swizzled ASYNC16 into linear [128][64] tiles. Read addr:
// [t*64 + ((chunk ^ (t&7))<<3)], chunk = (kk>>3)+quad; all read sites have t&7 == lr&7.
// LDS overlay: phase1 {qs[128][64], kbs[128][64]}; phase2 {Ps[128][136], vT[64][136]}.
// Union 26112 elems = 52.2 KB -> 3 blocks/CU.
__global__ __launch_bounds__(256, 3) void attn_chunk_kernel(const bf16* __restrict__ qkv,
                                                            const bf16* __restrict__ kvst,
                                                            bf16* __restrict__ outb) {
    const int c = blockIdx.x, h = blockIdx.y, b = blockIdx.z;
    const int g = h >> 2;
    const float slope = exp2f(-0.5f * (float)(h + 1));
    __shared__ bf16 smem[26112];
    bf16* qs  = smem;            // phase1: [128][64] chunk-XOR swizzled
    bf16* kbs = smem + 8192;     // phase1: [128][64] chunk-XOR swizzled
    bf16* Ps  = smem;            // phase2: [128][136] swizzled
    bf16* vT  = smem + 17408;    // phase2: [64][136] swizzled
    const int tid = threadIdx.x;
    const int wave = tid >> 6, lane = tid & 63, lr = lane & 15, quad = lane >> 4;
    const int srow = lane >> 3;                  // 0..7
    const int schunk = ((lane & 7) ^ srow) * 8;  // pre-swizzled source chunk (elems)
#pragma unroll
    for (int p = 0; p < 4; ++p) {
        int t0 = wave * 8 + p * 32;
        size_t row = (size_t)(b * S_ + c * 128 + t0 + srow);
        ASYNC16(qkv + row * 1536 + h * 64 + schunk, &qs[t0 * 64]);
        ASYNC16(qkv + row * 1536 + 1024 + g * 64 + schunk, &kbs[t0 * 64]);
    }
    asm volatile("s_waitcnt vmcnt(0)");
    __syncthreads();
    const int m0 = wave * 32;
    f32x4 sacc[2][8] = {};
#pragma unroll
    for (int kk = 0; kk < 64; kk += 32) {
        const int sw = ((((kk >> 3) + quad) ^ (lr & 7)) & 7) << 3;
        bf16x8 af0 = *(const bf16x8*)(&qs[(m0 + lr) * 64 + sw]);
        bf16x8 af1 = *(const bf16x8*)(&qs[(m0 + 16 + lr) * 64 + sw]);
#pragma unroll
        for (int ni = 0; ni < 8; ++ni) {
            bf16x8 bfr = *(const bf16x8*)(&kbs[(ni * 16 + lr) * 64 + sw]);
            sacc[0][ni] = __builtin_amdgcn_mfma_f32_16x16x32_bf16(af0, bfr, sacc[0][ni], 0, 0, 0);
            sacc[1][ni] = __builtin_amdgcn_mfma_f32_16x16x32_bf16(af1, bfr, sacc[1][ni], 0, 0, 0);
        }
    }
    // qKV term (qs still live; global kv-state loads overlap)
    f32x4 oacc[2][4] = {};
    const bf16* kvb = kvst + ((size_t)((b * NH_ + h) * NC_ + c)) * 4096;
    float qd0 = __expf(-slope * (float)(m0 + lr + 1));
    float qd1 = __expf(-slope * (float)(m0 + 16 + lr + 1));
#pragma unroll
    for (int kk = 0; kk < 64; kk += 32) {
        const int sw = ((((kk >> 3) + quad) ^ (lr & 7)) & 7) << 3;
        bf16x8 a0 = *(const bf16x8*)(&qs[(m0 + lr) * 64 + sw]);
        bf16x8 a1 = *(const bf16x8*)(&qs[(m0 + 16 + lr) * 64 + sw]);
#pragma unroll
        for (int i = 0; i < 8; ++i) {
            a0[i] = (__bf16)((float)a0[i] * qd0);
            a1[i] = (__bf16)((float)a1[i] * qd1);
        }
#pragma unroll
        for (int ni = 0; ni < 4; ++ni) {
            bf16x8 bk = *(const bf16x8*)(kvb + (ni * 16 + lr) * 64 + kk + quad * 8);
            oacc[0][ni] = __builtin_amdgcn_mfma_f32_16x16x32_bf16(a0, bk, oacc[0][ni], 0, 0, 0);
            oacc[1][ni] = __builtin_amdgcn_mfma_f32_16x16x32_bf16(a1, bk, oacc[1][ni], 0, 0, 0);
        }
    }
    __syncthreads();  // qs/kbs fully consumed; region reused for Ps/vT
    // factorized mask: exp(-s*(t-tp)) = exp(-s*(t-m0)) * exp(-s*max(m0-tp,-31))
    float ftv[2][4], gtv[8];
#pragma unroll
    for (int mi = 0; mi < 2; ++mi)
#pragma unroll
        for (int r = 0; r < 4; ++r) ftv[mi][r] = __expf(-slope * (float)(mi * 16 + quad * 4 + r));
#pragma unroll
    for (int ni = 0; ni < 8; ++ni)
        gtv[ni] = __expf(-slope * fmaxf((float)(m0 - (ni * 16 + lr)), -31.0f));
#pragma unroll
    for (int mi = 0; mi < 2; ++mi)
#pragma unroll
        for (int ni = 0; ni < 8; ++ni)
#pragma unroll
            for (int r = 0; r < 4; ++r) {
                int t = m0 + mi * 16 + quad * 4 + r;
                int tp = ni * 16 + lr;
                float val = (t >= tp) ? sacc[mi][ni][r] * ftv[mi][r] * gtv[ni] : 0.f;
                int sw = (((tp >> 3) & ~7) << 3) + ((((tp >> 3) ^ (t >> 3)) & 7) << 3) + (tp & 7);
                Ps[t * 136 + sw] = __float2bfloat16(val);
            }
    // stage v transposed (swizzled)
#pragma unroll
    for (int p = 0; p < 4; ++p) {
        int flat = p * 256 + tid;
        int t = flat >> 3, d0 = (flat & 7) * 8;
        size_t row = (size_t)(b * S_ + c * 128 + t);
        uint4 vw = *(const uint4*)(qkv + row * 1536 + 1280 + g * 64 + d0);
        const bf16* vp = (const bf16*)&vw;
#pragma unroll
        for (int i = 0; i < 8; ++i) {
            int e = d0 + i;
            int sw = (((t >> 3) & ~7) << 3) + ((((t >> 3) ^ (e >> 3)) & 7) << 3) + (t & 7);
            vT[e * 136 + sw] = vp[i];
        }
    }
    __syncthreads();
#pragma unroll
    for (int ks2 = 0; ks2 < 128; ks2 += 32) {
        int qa = (ks2 >> 3) + quad;             // chunk index 0..15
        int qhi = (qa & ~7) << 3;
        int ra0 = m0 + lr, ra1 = m0 + 16 + lr;
        bf16x8 af0 = *(const bf16x8*)(&Ps[ra0 * 136 + qhi + (((qa ^ (ra0 >> 3)) & 7) << 3)]);
        bf16x8 af1 = *(const bf16x8*)(&Ps[ra1 * 136 + qhi + (((qa ^ (ra1 >> 3)) & 7) << 3)]);
#pragma unroll
        for (int ni = 0; ni < 4; ++ni) {
            int eb = ni * 16 + lr;
            bf16x8 bfv = *(const bf16x8*)(&vT[eb * 136 + qhi + (((qa ^ (eb >> 3)) & 7) << 3)]);
            oacc[0][ni] = __builtin_amdgcn_mfma_f32_16x16x32_bf16(af0, bfv, oacc[0][ni], 0, 0, 0);
            oacc[1][ni] = __builtin_amdgcn_mfma_f32_16x16x32_bf16(af1, bfv, oacc[1][ni], 0, 0, 0);
        }
    }
#pragma unroll
    for (int mi = 0; mi < 2; ++mi)
#pragma unroll
        for (int ni = 0; ni < 4; ++ni)
#pragma unroll
            for (int r = 0; r < 4; ++r) {
                int t = m0 + mi * 16 + quad * 4 + r;
                int e = ni * 16 + lr;
                size_t row = (size_t)(b * S_ + c * 128 + t);
                outb[row * (NH_ * 64) + h * 64 + e] = __float2bfloat16(oacc[mi][ni][r]);
            }
}

extern "C" void kernel_launch(void* const* d_in, const int* in_sizes, int n_in,
                              void* d_out, int out_size, void* d_ws, size_t ws_size,
                              hipStream_t stream) {
    (void)in_sizes; (void)n_in; (void)out_size; (void)ws_size;
    const float* x  = (const float*)d_in[0];
    const float* Wq = (const float*)d_in[1];
    const float* Wk = (const float*)d_in[2];
    const float* Wv = (const float*)d_in[3];
    const float* Wo = (const float*)d_in[4];
    float* out = (float*)d_out;
    char* ws = (char*)d_ws;
    bf16*  xb    = (bf16*)(ws);                    // 33,554,432 (reused as attn_out)
    bf16*  qkvb  = (bf16*)(ws + 33554432);         // 50,331,648  [M][1536]: q|k|v
    bf16*  wqkvb = (bf16*)(ws + 83886080);         //  3,145,728  [1536][1024]
    bf16*  wob   = (bf16*)(ws + 87031808);         //  2,097,152
    float* cosd  = (float*)(ws + 89128960);        //  1,048,576
    float* sind  = (float*)(ws + 90177536);        //  1,048,576
    bf16*  Cbuf  = (bf16*)(ws + 91226112);         // 16,777,216
    bf16*  kvst  = (bf16*)(ws + 108003328);        // 16,777,216  -> total 124,780,544 B
    bf16*  attn  = xb;

    prep_kernel<<<19968, 256, 0, stream>>>(x, Wq, Wk, Wv, Wo, xb, wqkvb, wob, cosd, sind);

    // fused q|k|v projection with RoPE on cols < 1280; 1536 blocks @ 3/CU = 2.0 exact rounds
    gemm_bt_kernel<bf16, 3><<<dim3(128, 12), 256, 0, stream>>>(xb, wqkvb, qkvb, 16384, 1536, 1024, 1280, cosd, sind);

    // per-GROUP chunk KV (4 heads/block, raw k/v staged once)
    chunk_kv_kernel<<<dim3(NC_, NKV_, B_), 512, 0, stream>>>(qkvb, Cbuf);
    scan_kv_kernel<<<512, 256, 0, stream>>>(Cbuf, kvst);
    attn_chunk_kernel<<<dim3(NC_, NH_, B_), 256, 0, stream>>>(qkvb, kvst, attn);

    // output projection; 1024 blocks @ 4/CU = 1.0 exact round (was 1.33 @ 3/CU -> full-round tail)
    gemm_bt_kernel<float, 4><<<dim3(128, 8), 256, 0, stream>>>(attn, wob, out, 16384, 1024, 1024, 0, cosd, sind);
}